// Round 10
// baseline (782.849 us; speedup 1.0000x reference)
//
#include <hip/hip_runtime.h>

#define AS1 __attribute__((address_space(1)))
#define AS3 __attribute__((address_space(3)))

typedef __bf16 bf16;
typedef unsigned char u8;
typedef unsigned int u32;
typedef __bf16 bf16x8 __attribute__((ext_vector_type(8)));
typedef __bf16 bf16x4v __attribute__((ext_vector_type(4)));
typedef float  f32x4  __attribute__((ext_vector_type(4)));

#define MFMA16(a,b,c) __builtin_amdgcn_mfma_f32_16x16x32_bf16((a),(b),(c),0,0,0)
#define MFMAF8(a,b,c) __builtin_amdgcn_mfma_f32_16x16x32_fp8_fp8((a),(b),(c),0,0,0)
#define BARX() asm volatile("s_waitcnt lgkmcnt(0)\ns_barrier" ::: "memory")
#define VMW(n) asm volatile("s_waitcnt vmcnt(" #n ")" ::: "memory")

static __device__ __forceinline__ void gll16(const bf16* src, bf16* lds) {
  __builtin_amdgcn_global_load_lds((const AS1 void*)src, (AS3 void*)lds, 16, 0, 0);
}
static __device__ __forceinline__ void gll16b(const u8* src, u8* lds) {
  __builtin_amdgcn_global_load_lds((const AS1 void*)src, (AS3 void*)lds, 16, 0, 0);
}

// ---------------- Kernel 0: weights fp32 -> bf16 ----------------
__global__ void convw_k(const float* __restrict__ s, bf16* __restrict__ d) {
  int i = (blockIdx.x * 256 + threadIdx.x) * 4;
  float4 v = *(const float4*)(s + i);
  bf16x4v o;
  o[0] = (bf16)v.x; o[1] = (bf16)v.y; o[2] = (bf16)v.z; o[3] = (bf16)v.w;
  *(bf16x4v*)(d + i) = o;
}

// ------------- Kernel 1: transpose+convert feat [B,C,4096] -> [B,4096,C] bf16 -------------
__global__ void tconv_k(const float* __restrict__ f0, const float* __restrict__ f1,
                        bf16* __restrict__ xq, bf16* __restrict__ xkv) {
  const int z = blockIdx.z;
  const int b = z & 7;
  const float* src = (z < 8) ? f0 : f1;
  bf16* dst = (z < 8) ? xq : xkv;
  const int n0 = blockIdx.x * 32, c0 = blockIdx.y * 32;
  __shared__ float tile[32][33];
  const int tx = threadIdx.x, ty = threadIdx.y;
  const size_t base = (size_t)b * 512 * 4096;
#pragma unroll
  for (int i = 0; i < 4; i++) {
    int c = ty + i * 8;
    tile[c][tx] = src[base + (size_t)(c0 + c) * 4096 + n0 + tx];
  }
  __syncthreads();
  const size_t ob = (size_t)b * 4096 * 512;
#pragma unroll
  for (int i = 0; i < 4; i++) {
    int n = ty + i * 8;
    dst[ob + (size_t)(n0 + n) * 512 + c0 + tx] = (bf16)tile[tx][n];
  }
}

// ------------- Kernel 2: generic GEMM  out[r,co] = sum_k A[r,k]*W[co,k] + bias[co] -------------
// MODE 0: out bf16 [B,4096,512] plain                  (Q, K)
// MODE 1: out fp8 e4m3 image [B][tile=kv>>5][g=(kv&31)>>3][co 512][byte=kv&7]  (V image)
// MODE 2: out fp32 transposed [B,512,4096] + residual feat0  (final)
template<int MODE>
__global__ __launch_bounds__(256) void gemm_k(const bf16* __restrict__ A, const bf16* __restrict__ W,
                                              const float* __restrict__ bias, bf16* __restrict__ outB,
                                              float* __restrict__ outF, const float* __restrict__ resid) {
  const int b = blockIdx.y;
  const int rt = blockIdx.x >> 2, ct = blockIdx.x & 3;
  const int r0 = rt * 128, c0 = ct * 128;
  const int t = threadIdx.x, w = t >> 6, l = t & 63;
  __shared__ alignas(16) bf16 As[128 * 32];
  __shared__ alignas(16) bf16 Bs[128 * 32];
  f32x4 acc[4][4];
  const f32x4 fzero = {0.f, 0.f, 0.f, 0.f};
#pragma unroll
  for (int m = 0; m < 4; m++)
#pragma unroll
    for (int n = 0; n < 4; n++) acc[m][n] = fzero;
  const bf16* Ab = A + (size_t)b * 4096 * 512 + (size_t)r0 * 512;
  const int wr = (w >> 1) * 64, wc = (w & 1) * 64;
  for (int kk = 0; kk < 16; kk++) {
    const int k0 = kk * 32;
#pragma unroll
    for (int h = 0; h < 2; h++) {
      const int rowbase = w * 32 + h * 16;
      const int row = rowbase + (l >> 2);
      const int cl = (l & 3) ^ ((row >> 1) & 3);
      gll16(Ab + (size_t)row * 512 + k0 + cl * 8, As + rowbase * 32);
      gll16(W + (size_t)(c0 + row) * 512 + k0 + cl * 8, Bs + rowbase * 32);
    }
    __syncthreads();
    bf16x8 af[4], bfr[4];
#pragma unroll
    for (int m = 0; m < 4; m++) {
      const int row = wr + m * 16 + (l & 15);
      af[m] = *(const bf16x8*)(As + row * 32 + (((l >> 4) ^ ((row >> 1) & 3)) << 3));
    }
#pragma unroll
    for (int n = 0; n < 4; n++) {
      const int row = wc + n * 16 + (l & 15);
      bfr[n] = *(const bf16x8*)(Bs + row * 32 + (((l >> 4) ^ ((row >> 1) & 3)) << 3));
    }
#pragma unroll
    for (int m = 0; m < 4; m++)
#pragma unroll
      for (int n = 0; n < 4; n++)
        acc[m][n] = MFMA16(af[m], bfr[n], acc[m][n]);
    __syncthreads();
  }
#pragma unroll
  for (int n = 0; n < 4; n++) {
    const int co = c0 + wc + n * 16 + (l & 15);
    const float bv = bias[co];
#pragma unroll
    for (int m = 0; m < 4; m++) {
      const int rb = r0 + wr + m * 16 + ((l >> 4) << 2);
      if constexpr (MODE == 0) {
#pragma unroll
        for (int i = 0; i < 4; i++)
          outB[(size_t)b * 4096 * 512 + (size_t)(rb + i) * 512 + co] = (bf16)(acc[m][n][i] + bv);
      } else if constexpr (MODE == 1) {
        // V image: fp8 e4m3, [B][rb>>5][g=(rb&31)>>3][co][rb&7]; 4 kv per int store
        int pw = 0;
        pw = __builtin_amdgcn_cvt_pk_fp8_f32(acc[m][n][0] + bv, acc[m][n][1] + bv, pw, false);
        pw = __builtin_amdgcn_cvt_pk_fp8_f32(acc[m][n][2] + bv, acc[m][n][3] + bv, pw, true);
        const int kvin = rb & 31;
        u8* ov = (u8*)outB;
        const size_t o = (((size_t)b * 128 + (rb >> 5)) * 4 + (kvin >> 3)) * 4096 + (size_t)co * 8 + (kvin & 7);
        *(int*)(ov + o) = pw;
      } else {
        const size_t o = ((size_t)b * 512 + co) * 4096 + rb;
        float4 rv = *(const float4*)(resid + o);
        float4 ov;
        ov.x = acc[m][n][0] + bv + rv.x;
        ov.y = acc[m][n][1] + bv + rv.y;
        ov.z = acc[m][n][2] + bv + rv.z;
        ov.w = acc[m][n][3] + bv + rv.w;
        *(float4*)(outF + o) = ov;
      }
    }
  }
}

// ------------- Kernel 3: flash cross-attention, 4 waves x 64 q, 2 blocks/CU (TLP) -------------
// Q [B,4096,512] bf16; K [B,4096,512] bf16 (source-swizzled staging, dbuf); V fp8 image
// [B][128][4 g][512 co][8] (single buf, 2-barrier discipline). LDS = 64+16 = 80 KiB.
__global__ __launch_bounds__(256, 2) void flash_k(const bf16* __restrict__ Q, const bf16* __restrict__ K,
                                                  const u8* __restrict__ Vt, bf16* __restrict__ ctx) {
  __shared__ alignas(16) bf16 Ks[2][32 * 512];   // 64 KB K double-buffer
  __shared__ alignas(16) u8   Vs[16384];         // 16 KB V single buffer
  const int flat = blockIdx.x;
  const int fs = (flat & 7) * 64 + (flat >> 3);  // XCD swizzle (512 = 8*64, bijective); batch->XCD
  const int b = fs >> 6, n0 = (fs & 63) * 64;
  const int tid = threadIdx.x, w = tid >> 6, l = tid & 63;
  const int g = l >> 4, r16 = l & 15;
  const int kswz = r16 & 7;

  // Q fragments (B-operand): lane holds Q[n0+w*16+r16][f*32 + g*8 .. +7]
  bf16x8 qf[16];
  {
    const bf16* Qb = Q + ((size_t)b * 4096 + n0 + w * 16 + r16) * 512 + g * 8;
#pragma unroll
    for (int f = 0; f < 16; f++) qf[f] = *(const bf16x8*)(Qb + f * 32);
  }
  f32x4 acc[32];
  const f32x4 fz = {0.f, 0.f, 0.f, 0.f};
#pragma unroll
  for (int f = 0; f < 32; f++) acc[f] = fz;
  float mrow = -1e30f, lrow = 0.f;

  // staging offsets (tile-invariant). K: LDS row linear, source chunk ^ (row&7). 8 rows/wave.
  int koff[8];
#pragma unroll
  for (int j = 0; j < 8; j++) {
    const int row = w * 8 + j;
    koff[j] = row * 512 + ((l ^ (row & 7)) << 3);
  }
  const int voff0 = w * 4096 + l * 16;           // V: fully linear (image pre-arranged), 4 ops/wave
  const bf16* Kg = K + (size_t)b * 4096 * 512;
  const u8* Vg = Vt + (size_t)b * 128 * 16384;
  VMW(0);  // drain qf loads

  // prologue: stage K(0) into buf 0 and V(0)
#pragma unroll
  for (int j = 0; j < 8; j++) gll16(Kg + koff[j], &Ks[0][0] + (w * 8 + j) * 512);
#pragma unroll
  for (int j = 0; j < 4; j++) gll16b(Vg + voff0 + j * 1024, Vs + voff0 + j * 1024);

#pragma unroll 1
  for (int t = 0; t < 128; ++t) {
    VMW(0);     // K(t) + V(t) landed
    BARX();     // all waves' tile-t data visible
    // ---- stage K(t+1) into other buffer (overlaps QK/softmax/PV below) ----
    if (t < 127) {
      const bf16* ks = Kg + (size_t)(t + 1) * 16384;
      bf16* kd = &Ks[(t + 1) & 1][0];
#pragma unroll
      for (int j = 0; j < 8; j++) gll16(ks + koff[j], kd + (w * 8 + j) * 512);
    }

    // ---- QK^T: S^T[key][q], 4 independent MFMA chains ----
    const bf16* kb0 = &Ks[t & 1][0] + r16 * 512;
    f32x4 sa = fz, sb = fz, sc2 = fz, sd = fz;
#pragma unroll
    for (int f2 = 0; f2 < 16; f2 += 2) {
      const int c0i = ((((f2 << 2) + g) ^ kswz) << 3);
      const int c1i = (((((f2 + 1) << 2) + g) ^ kswz) << 3);
      bf16x8 k0 = *(const bf16x8*)(kb0 + c0i);
      bf16x8 k1 = *(const bf16x8*)(kb0 + 16 * 512 + c0i);
      bf16x8 k2 = *(const bf16x8*)(kb0 + c1i);
      bf16x8 k3 = *(const bf16x8*)(kb0 + 16 * 512 + c1i);
      sa = MFMA16(k0, qf[f2], sa);
      sb = MFMA16(k1, qf[f2], sb);
      sc2 = MFMA16(k2, qf[f2 + 1], sc2);
      sd = MFMA16(k3, qf[f2 + 1], sd);
    }
    const f32x4 s0 = sa + sc2, s1 = sb + sd;   // lane(q=r16): keys 4g+i / 16+4g+i

    // ---- online softmax, defer-max THR=5 (P <= e^5 = 148 < fp8 max 448) ----
    float pmax = fmaxf(fmaxf(fmaxf(s0[0], s0[1]), fmaxf(s0[2], s0[3])),
                       fmaxf(fmaxf(s1[0], s1[1]), fmaxf(s1[2], s1[3])));
    pmax = fmaxf(pmax, __shfl_xor(pmax, 16));
    pmax = fmaxf(pmax, __shfl_xor(pmax, 32));
    if (!__all(pmax <= mrow + 5.0f)) {
      const float mnew = fmaxf(mrow, pmax);
      const float scl = __expf(mrow - mnew);
      mrow = mnew;
      lrow *= scl;
      const int sclI = __float_as_int(scl);
      f32x4 sc4;
#pragma unroll
      for (int i = 0; i < 4; i++)
        sc4[i] = __int_as_float(__builtin_amdgcn_ds_bpermute(((g << 2) + i) << 2, sclI));
#pragma unroll
      for (int f = 0; f < 32; f++) acc[f] *= sc4;
    }
    float p0[4], p1[4];
#pragma unroll
    for (int i = 0; i < 4; i++) { p0[i] = __expf(s0[i] - mrow); p1[i] = __expf(s1[i] - mrow); }
    float rs = (p0[0] + p0[1]) + (p0[2] + p0[3]) + (p1[0] + p1[1]) + (p1[2] + p1[3]);
    rs += __shfl_xor(rs, 16);
    rs += __shfl_xor(rs, 32);
    lrow += rs;

    // ---- pack P->fp8, redistribute to PV A-fragment (4 bpermutes, register-only) ----
    int w0 = 0, w1 = 0;
    w0 = __builtin_amdgcn_cvt_pk_fp8_f32(p0[0], p0[1], w0, false);
    w0 = __builtin_amdgcn_cvt_pk_fp8_f32(p0[2], p0[3], w0, true);
    w1 = __builtin_amdgcn_cvt_pk_fp8_f32(p1[0], p1[1], w1, false);
    w1 = __builtin_amdgcn_cvt_pk_fp8_f32(p1[2], p1[3], w1, true);
    const int addrA = (((g & 1) << 5) + r16) << 2;   // lane 32*(g&1) + r16
    const int addrB = addrA + 64;                    // +16 lanes
    const int a0 = __builtin_amdgcn_ds_bpermute(addrA, w0);
    const int b0 = __builtin_amdgcn_ds_bpermute(addrB, w0);
    const int a1 = __builtin_amdgcn_ds_bpermute(addrA, w1);
    const int b1 = __builtin_amdgcn_ds_bpermute(addrB, w1);
    const bool lo2 = (g < 2);
    const u32 pA = (u32)(lo2 ? a0 : a1);
    const u32 pB = (u32)(lo2 ? b0 : b1);
    const long pf = (long)(((unsigned long long)pB << 32) | pA);

    // ---- PV: acc += P(fp8) @ V(fp8 in LDS); lane B-frag: keys g*8..+7, co = ct*16+r16 ----
    const u8* vb = Vs + g * 4096 + r16 * 8;
    __builtin_amdgcn_s_setprio(1);
#pragma unroll
    for (int ct = 0; ct < 32; ct++) {
      const long vf = *(const long*)(vb + ct * 128);
      acc[ct] = MFMAF8(pf, vf, acc[ct]);
    }
    __builtin_amdgcn_s_setprio(0);
    BARX();   // all PV reads of Vs done before restage
    // ---- stage V(t+1) into the single buffer ----
    if (t < 127) {
      const u8* vs = Vg + (size_t)(t + 1) * 16384;
#pragma unroll
      for (int j = 0; j < 4; j++) gll16b(vs + voff0 + j * 1024, Vs + voff0 + j * 1024);
    }
  }

  // ---- epilogue: ctx = acc / lrow * C^-0.5 ----
  const float inv = 0.04419417382415922f / lrow;
  const int invI = __float_as_int(inv);
  float fin[4];
#pragma unroll
  for (int i = 0; i < 4; i++)
    fin[i] = __int_as_float(__builtin_amdgcn_ds_bpermute(((g << 2) + i) << 2, invI));
  const size_t ob = (size_t)b * 4096 * 512;
#pragma unroll
  for (int ct = 0; ct < 32; ct++) {
    const int c = (ct << 4) + r16;
#pragma unroll
    for (int i = 0; i < 4; i++) {
      const int n = n0 + w * 16 + (g << 2) + i;
      ctx[ob + (size_t)n * 512 + c] = (bf16)(acc[ct][i] * fin[i]);
    }
  }
}

extern "C" void kernel_launch(void* const* d_in, const int* in_sizes, int n_in,
                              void* d_out, int out_size, void* d_ws, size_t ws_size,
                              hipStream_t stream) {
  const float* feat0 = (const float*)d_in[0];
  const float* feat1 = (const float*)d_in[1];
  const float* Wq = (const float*)d_in[2];
  const float* bq = (const float*)d_in[3];
  const float* Wk = (const float*)d_in[4];
  const float* bk = (const float*)d_in[5];
  const float* Wv = (const float*)d_in[6];
  const float* bv = (const float*)d_in[7];
  const float* Wo = (const float*)d_in[8];
  const float* bo = (const float*)d_in[9];
  float* out = (float*)d_out;

  char* ws = (char*)d_ws;
  bf16* Wqb = (bf16*)(ws);
  bf16* Wkb = (bf16*)(ws + (1 << 19));
  bf16* Wvb = (bf16*)(ws + 2 * (size_t)(1 << 19));
  bf16* Wob = (bf16*)(ws + 3 * (size_t)(1 << 19));
  const size_t TEN = (size_t)8 * 4096 * 512 * 2;  // 33.55 MB per bf16 tensor
  char* p = ws + 4 * (size_t)(1 << 19);
  bf16* Xq  = (bf16*)(p);
  bf16* Xkv = (bf16*)(p + TEN);
  bf16* Qb  = (bf16*)(p + 2 * TEN);
  bf16* Kb  = (bf16*)(p + 3 * TEN);
  bf16* Vtb = (bf16*)(p + 4 * TEN);   // fp8 image (16 MB)
  bf16* ctx = Xq;  // Xq dead after Q projection

  convw_k<<<256, 256, 0, stream>>>(Wq, Wqb);
  convw_k<<<256, 256, 0, stream>>>(Wk, Wkb);
  convw_k<<<256, 256, 0, stream>>>(Wv, Wvb);
  convw_k<<<256, 256, 0, stream>>>(Wo, Wob);
  tconv_k<<<dim3(128, 16, 16), dim3(32, 8), 0, stream>>>(feat0, feat1, Xq, Xkv);
  gemm_k<0><<<dim3(128, 8), 256, 0, stream>>>(Xq,  Wqb, bq, Qb,  nullptr, nullptr);
  gemm_k<0><<<dim3(128, 8), 256, 0, stream>>>(Xkv, Wkb, bk, Kb,  nullptr, nullptr);
  gemm_k<1><<<dim3(128, 8), 256, 0, stream>>>(Xkv, Wvb, bv, Vtb, nullptr, nullptr);
  flash_k<<<dim3(512), dim3(256), 0, stream>>>(Qb, Kb, (const u8*)Vtb, ctx);
  gemm_k<2><<<dim3(128, 8), 256, 0, stream>>>(ctx, Wob, bo, nullptr, out, feat0);
}

// Round 11
// 623.768 us; speedup vs baseline: 1.2550x; 1.2550x over previous
//
#include <hip/hip_runtime.h>

#define AS1 __attribute__((address_space(1)))
#define AS3 __attribute__((address_space(3)))

typedef __bf16 bf16;
typedef unsigned char u8;
typedef unsigned int u32;
typedef __bf16 bf16x8 __attribute__((ext_vector_type(8)));
typedef __bf16 bf16x4v __attribute__((ext_vector_type(4)));
typedef float  f32x4  __attribute__((ext_vector_type(4)));

#define MFMA16(a,b,c) __builtin_amdgcn_mfma_f32_16x16x32_bf16((a),(b),(c),0,0,0)
#define MFMAF8(a,b,c) __builtin_amdgcn_mfma_f32_16x16x32_fp8_fp8((a),(b),(c),0,0,0)
#define BARX() asm volatile("s_waitcnt lgkmcnt(0)\ns_barrier" ::: "memory")
#define VMW(n) asm volatile("s_waitcnt vmcnt(" #n ")" ::: "memory")

static __device__ __forceinline__ void gll16(const bf16* src, bf16* lds) {
  __builtin_amdgcn_global_load_lds((const AS1 void*)src, (AS3 void*)lds, 16, 0, 0);
}
static __device__ __forceinline__ void gll16b(const u8* src, u8* lds) {
  __builtin_amdgcn_global_load_lds((const AS1 void*)src, (AS3 void*)lds, 16, 0, 0);
}

// ---------------- Kernel 0: weights fp32 -> bf16 ----------------
__global__ void convw_k(const float* __restrict__ s, bf16* __restrict__ d) {
  int i = (blockIdx.x * 256 + threadIdx.x) * 4;
  float4 v = *(const float4*)(s + i);
  bf16x4v o;
  o[0] = (bf16)v.x; o[1] = (bf16)v.y; o[2] = (bf16)v.z; o[3] = (bf16)v.w;
  *(bf16x4v*)(d + i) = o;
}

// ------------- Kernel 1: transpose+convert feat [B,C,4096] -> [B,4096,C] bf16 -------------
__global__ void tconv_k(const float* __restrict__ f0, const float* __restrict__ f1,
                        bf16* __restrict__ xq, bf16* __restrict__ xkv) {
  const int z = blockIdx.z;
  const int b = z & 7;
  const float* src = (z < 8) ? f0 : f1;
  bf16* dst = (z < 8) ? xq : xkv;
  const int n0 = blockIdx.x * 32, c0 = blockIdx.y * 32;
  __shared__ float tile[32][33];
  const int tx = threadIdx.x, ty = threadIdx.y;
  const size_t base = (size_t)b * 512 * 4096;
#pragma unroll
  for (int i = 0; i < 4; i++) {
    int c = ty + i * 8;
    tile[c][tx] = src[base + (size_t)(c0 + c) * 4096 + n0 + tx];
  }
  __syncthreads();
  const size_t ob = (size_t)b * 4096 * 512;
#pragma unroll
  for (int i = 0; i < 4; i++) {
    int n = ty + i * 8;
    dst[ob + (size_t)(n0 + n) * 512 + c0 + tx] = (bf16)tile[tx][n];
  }
}

// ------------- Kernel 2: generic GEMM  out[r,co] = sum_k A[r,k]*W[co,k] + bias[co] -------------
// MODE 0: out bf16 [B,4096,512] plain                  (Q, K)
// MODE 1: out fp8 e4m3 image [B][tile=kv>>6][g=(kv>>3)&7][co 512][byte=kv&7]  (V image, BK=64)
// MODE 2: out fp32 transposed [B,512,4096] + residual feat0  (final)
template<int MODE>
__global__ __launch_bounds__(256) void gemm_k(const bf16* __restrict__ A, const bf16* __restrict__ W,
                                              const float* __restrict__ bias, bf16* __restrict__ outB,
                                              float* __restrict__ outF, const float* __restrict__ resid) {
  const int b = blockIdx.y;
  const int rt = blockIdx.x >> 2, ct = blockIdx.x & 3;
  const int r0 = rt * 128, c0 = ct * 128;
  const int t = threadIdx.x, w = t >> 6, l = t & 63;
  __shared__ alignas(16) bf16 As[128 * 32];
  __shared__ alignas(16) bf16 Bs[128 * 32];
  f32x4 acc[4][4];
  const f32x4 fzero = {0.f, 0.f, 0.f, 0.f};
#pragma unroll
  for (int m = 0; m < 4; m++)
#pragma unroll
    for (int n = 0; n < 4; n++) acc[m][n] = fzero;
  const bf16* Ab = A + (size_t)b * 4096 * 512 + (size_t)r0 * 512;
  const int wr = (w >> 1) * 64, wc = (w & 1) * 64;
  for (int kk = 0; kk < 16; kk++) {
    const int k0 = kk * 32;
#pragma unroll
    for (int h = 0; h < 2; h++) {
      const int rowbase = w * 32 + h * 16;
      const int row = rowbase + (l >> 2);
      const int cl = (l & 3) ^ ((row >> 1) & 3);
      gll16(Ab + (size_t)row * 512 + k0 + cl * 8, As + rowbase * 32);
      gll16(W + (size_t)(c0 + row) * 512 + k0 + cl * 8, Bs + rowbase * 32);
    }
    __syncthreads();
    bf16x8 af[4], bfr[4];
#pragma unroll
    for (int m = 0; m < 4; m++) {
      const int row = wr + m * 16 + (l & 15);
      af[m] = *(const bf16x8*)(As + row * 32 + (((l >> 4) ^ ((row >> 1) & 3)) << 3));
    }
#pragma unroll
    for (int n = 0; n < 4; n++) {
      const int row = wc + n * 16 + (l & 15);
      bfr[n] = *(const bf16x8*)(Bs + row * 32 + (((l >> 4) ^ ((row >> 1) & 3)) << 3));
    }
#pragma unroll
    for (int m = 0; m < 4; m++)
#pragma unroll
      for (int n = 0; n < 4; n++)
        acc[m][n] = MFMA16(af[m], bfr[n], acc[m][n]);
    __syncthreads();
  }
#pragma unroll
  for (int n = 0; n < 4; n++) {
    const int co = c0 + wc + n * 16 + (l & 15);
    const float bv = bias[co];
#pragma unroll
    for (int m = 0; m < 4; m++) {
      const int rb = r0 + wr + m * 16 + ((l >> 4) << 2);
      if constexpr (MODE == 0) {
#pragma unroll
        for (int i = 0; i < 4; i++)
          outB[(size_t)b * 4096 * 512 + (size_t)(rb + i) * 512 + co] = (bf16)(acc[m][n][i] + bv);
      } else if constexpr (MODE == 1) {
        // V image fp8 e4m3: [B][rb>>6][(rb>>3)&7][co][rb&7]; 4 kv per int store
        int pw = 0;
        pw = __builtin_amdgcn_cvt_pk_fp8_f32(acc[m][n][0] + bv, acc[m][n][1] + bv, pw, false);
        pw = __builtin_amdgcn_cvt_pk_fp8_f32(acc[m][n][2] + bv, acc[m][n][3] + bv, pw, true);
        u8* ov = (u8*)outB;
        const size_t o = (((size_t)b * 64 + (rb >> 6)) * 8 + ((rb >> 3) & 7)) * 4096 + (size_t)co * 8 + (rb & 7);
        *(int*)(ov + o) = pw;
      } else {
        const size_t o = ((size_t)b * 512 + co) * 4096 + rb;
        float4 rv = *(const float4*)(resid + o);
        float4 ov;
        ov.x = acc[m][n][0] + bv + rv.x;
        ov.y = acc[m][n][1] + bv + rv.y;
        ov.z = acc[m][n][2] + bv + rv.z;
        ov.w = acc[m][n][3] + bv + rv.w;
        *(float4*)(outF + o) = ov;
      }
    }
  }
}

// ------------- Kernel 3: flash cross-attention, BK=64 (R8 structure, overheads amortized) ------
// 8 waves x 16 q-rows = 128 q/block. Q [B,4096,512] bf16; K [B,4096,512] bf16, source-swizzled
// staging, 64-key dbuf (128 KB); V fp8 image [B][64][8 g][512 co][8] single 32 KB buffer.
// LDS = 160 KiB exactly. ctx = (softmax(QK^T)*C^-0.5) @ V.
__global__ __launch_bounds__(512, 2) void flash_k(const bf16* __restrict__ Q, const bf16* __restrict__ K,
                                                  const u8* __restrict__ Vt, bf16* __restrict__ ctx) {
  __shared__ alignas(16) bf16 Ks[2][64 * 512];   // 128 KB K double-buffer (64 keys/tile)
  __shared__ alignas(16) u8   Vs[8 * 4096];      // 32 KB V single buffer
  const int flat = blockIdx.x;
  const int fs = (flat & 7) * 32 + (flat >> 3);  // XCD swizzle (256 = 8*32, bijective)
  const int b = fs >> 5, n0 = (fs & 31) * 128;
  const int tid = threadIdx.x, w = tid >> 6, l = tid & 63;
  const int g = l >> 4, r16 = l & 15;
  const int kswz = r16 & 7;

  // Q fragments (B-operand): lane holds Q[n0+w*16+r16][f*32 + g*8 .. +7]
  bf16x8 qf[16];
  {
    const bf16* Qb = Q + ((size_t)b * 4096 + n0 + w * 16 + r16) * 512 + g * 8;
#pragma unroll
    for (int f = 0; f < 16; f++) qf[f] = *(const bf16x8*)(Qb + f * 32);
  }
  f32x4 acc[32];
  const f32x4 fz = {0.f, 0.f, 0.f, 0.f};
#pragma unroll
  for (int f = 0; f < 32; f++) acc[f] = fz;
  float mrow = -1e30f, lrow = 0.f;

  // staging offsets (tile-invariant). K: LDS row linear, source chunk ^ (row&7). 8 rows/wave.
  int koff[8];
#pragma unroll
  for (int j = 0; j < 8; j++) {
    const int row = w * 8 + j;
    koff[j] = row * 512 + ((l ^ (row & 7)) << 3);
  }
  const int voff0 = w * 4096 + l * 16;           // V: fully linear (image pre-arranged), 4 ops/wave
  const bf16* Kg = K + (size_t)b * 4096 * 512;
  const u8* Vg = Vt + (size_t)b * 64 * 32768;
  VMW(0);  // drain qf loads

  // prologue: stage K(0) into buf 0 and V(0)
#pragma unroll
  for (int j = 0; j < 8; j++) gll16(Kg + koff[j], &Ks[0][0] + (w * 8 + j) * 512);
#pragma unroll
  for (int j = 0; j < 4; j++) gll16b(Vg + voff0 + j * 1024, Vs + voff0 + j * 1024);

#pragma unroll 1
  for (int t = 0; t < 64; ++t) {
    VMW(0);     // K(t) (staged top of t-1, full iter of cover) + V(t) (staged bottom of t-1)
    BARX();     // all waves' tile-t data visible
    // ---- stage K(t+1) into other buffer (hides under this iter's compute) ----
    if (t < 63) {
      const bf16* ks = Kg + (size_t)(t + 1) * 32768;
      bf16* kd = &Ks[(t + 1) & 1][0];
#pragma unroll
      for (int j = 0; j < 8; j++) gll16(ks + koff[j], kd + (w * 8 + j) * 512);
    }

    // ---- QK^T: S^T[key][q], 4 independent chains over 4 key-rows (r16, +16, +32, +48) ----
    const bf16* kb0 = &Ks[t & 1][0] + r16 * 512;
    f32x4 s0 = fz, s1 = fz, s2 = fz, s3 = fz;
#pragma unroll
    for (int f2 = 0; f2 < 16; f2++) {
      const int ci = ((((f2 << 2) + g) ^ kswz) << 3);
      bf16x8 k0 = *(const bf16x8*)(kb0 + ci);
      bf16x8 k1 = *(const bf16x8*)(kb0 + 16 * 512 + ci);
      bf16x8 k2 = *(const bf16x8*)(kb0 + 32 * 512 + ci);
      bf16x8 k3 = *(const bf16x8*)(kb0 + 48 * 512 + ci);
      s0 = MFMA16(k0, qf[f2], s0);
      s1 = MFMA16(k1, qf[f2], s1);
      s2 = MFMA16(k2, qf[f2], s2);
      s3 = MFMA16(k3, qf[f2], s3);
    }
    // lane(q=r16): keys 16h + 4g + i in s{h}[i]

    // ---- online softmax over 16 scores, defer-max THR=5 (P <= e^5 < fp8 max 448) ----
    float pmax = fmaxf(fmaxf(fmaxf(fmaxf(s0[0], s0[1]), fmaxf(s0[2], s0[3])),
                             fmaxf(fmaxf(s1[0], s1[1]), fmaxf(s1[2], s1[3]))),
                       fmaxf(fmaxf(fmaxf(s2[0], s2[1]), fmaxf(s2[2], s2[3])),
                             fmaxf(fmaxf(s3[0], s3[1]), fmaxf(s3[2], s3[3]))));
    pmax = fmaxf(pmax, __shfl_xor(pmax, 16));
    pmax = fmaxf(pmax, __shfl_xor(pmax, 32));
    if (!__all(pmax <= mrow + 5.0f)) {
      const float mnew = fmaxf(mrow, pmax);
      const float scl = __expf(mrow - mnew);
      mrow = mnew;
      lrow *= scl;
      const int sclI = __float_as_int(scl);
      f32x4 sc4;
#pragma unroll
      for (int i = 0; i < 4; i++)
        sc4[i] = __int_as_float(__builtin_amdgcn_ds_bpermute(((g << 2) + i) << 2, sclI));
#pragma unroll
      for (int f = 0; f < 32; f++) acc[f] *= sc4;
    }
    float p0[4], p1[4], p2[4], p3[4];
#pragma unroll
    for (int i = 0; i < 4; i++) {
      p0[i] = __expf(s0[i] - mrow);
      p1[i] = __expf(s1[i] - mrow);
      p2[i] = __expf(s2[i] - mrow);
      p3[i] = __expf(s3[i] - mrow);
    }
    float rs = ((p0[0] + p0[1]) + (p0[2] + p0[3])) + ((p1[0] + p1[1]) + (p1[2] + p1[3])) +
               ((p2[0] + p2[1]) + (p2[2] + p2[3])) + ((p3[0] + p3[1]) + (p3[2] + p3[3]));
    rs += __shfl_xor(rs, 16);
    rs += __shfl_xor(rs, 32);
    lrow += rs;

    // ---- pack P->fp8 (4 words = 16 keys x 4), redistribute via 8 bpermutes ----
    int w0 = 0, w1 = 0, w2 = 0, w3 = 0;
    w0 = __builtin_amdgcn_cvt_pk_fp8_f32(p0[0], p0[1], w0, false);
    w0 = __builtin_amdgcn_cvt_pk_fp8_f32(p0[2], p0[3], w0, true);
    w1 = __builtin_amdgcn_cvt_pk_fp8_f32(p1[0], p1[1], w1, false);
    w1 = __builtin_amdgcn_cvt_pk_fp8_f32(p1[2], p1[3], w1, true);
    w2 = __builtin_amdgcn_cvt_pk_fp8_f32(p2[0], p2[1], w2, false);
    w2 = __builtin_amdgcn_cvt_pk_fp8_f32(p2[2], p2[3], w2, true);
    w3 = __builtin_amdgcn_cvt_pk_fp8_f32(p3[0], p3[1], w3, false);
    w3 = __builtin_amdgcn_cvt_pk_fp8_f32(p3[2], p3[3], w3, true);
    const int addrA = (((g & 1) << 5) + r16) << 2;   // lane 32*(g&1) + r16  (g_src = 2(g&1))
    const int addrB = addrA + 64;                    // +16 lanes            (g_src = 2(g&1)+1)
    const int a0 = __builtin_amdgcn_ds_bpermute(addrA, w0);
    const int b0 = __builtin_amdgcn_ds_bpermute(addrB, w0);
    const int a1 = __builtin_amdgcn_ds_bpermute(addrA, w1);
    const int b1 = __builtin_amdgcn_ds_bpermute(addrB, w1);
    const int a2 = __builtin_amdgcn_ds_bpermute(addrA, w2);
    const int b2 = __builtin_amdgcn_ds_bpermute(addrB, w2);
    const int a3 = __builtin_amdgcn_ds_bpermute(addrA, w3);
    const int b3 = __builtin_amdgcn_ds_bpermute(addrB, w3);
    const bool lo2 = (g < 2);
    // pf0: keys g*8..g*8+7 (first 32); pf1: keys 32+g*8..+7 (second 32)
    const u32 pA0 = (u32)(lo2 ? a0 : a1), pB0 = (u32)(lo2 ? b0 : b1);
    const u32 pA1 = (u32)(lo2 ? a2 : a3), pB1 = (u32)(lo2 ? b2 : b3);
    const long pf0 = (long)(((unsigned long long)pB0 << 32) | pA0);
    const long pf1 = (long)(((unsigned long long)pB1 << 32) | pA1);

    // ---- PV: acc += P(fp8) @ V(fp8 in LDS); 2 MFMAs per co-tile (key halves) ----
    const u8* vbA = Vs + g * 4096 + r16 * 8;
    const u8* vbB = Vs + (4 + g) * 4096 + r16 * 8;
    __builtin_amdgcn_s_setprio(1);
#pragma unroll
    for (int ct = 0; ct < 32; ct++) {
      const long vf0 = *(const long*)(vbA + ct * 128);
      const long vf1 = *(const long*)(vbB + ct * 128);
      acc[ct] = MFMAF8(pf0, vf0, acc[ct]);
      acc[ct] = MFMAF8(pf1, vf1, acc[ct]);
    }
    __builtin_amdgcn_s_setprio(0);
    BARX();   // all PV reads of Vs done before restage
    // ---- stage V(t+1) into the single buffer ----
    if (t < 63) {
      const u8* vs = Vg + (size_t)(t + 1) * 32768;
#pragma unroll
      for (int j = 0; j < 4; j++) gll16b(vs + voff0 + j * 1024, Vs + voff0 + j * 1024);
    }
  }

  // ---- epilogue: ctx = acc / lrow * C^-0.5 ----
  const float inv = 0.04419417382415922f / lrow;
  const int invI = __float_as_int(inv);
  float fin[4];
#pragma unroll
  for (int i = 0; i < 4; i++)
    fin[i] = __int_as_float(__builtin_amdgcn_ds_bpermute(((g << 2) + i) << 2, invI));
  const size_t ob = (size_t)b * 4096 * 512;
#pragma unroll
  for (int ct = 0; ct < 32; ct++) {
    const int c = (ct << 4) + r16;
#pragma unroll
    for (int i = 0; i < 4; i++) {
      const int n = n0 + w * 16 + (g << 2) + i;
      ctx[ob + (size_t)n * 512 + c] = (bf16)(acc[ct][i] * fin[i]);
    }
  }
}

extern "C" void kernel_launch(void* const* d_in, const int* in_sizes, int n_in,
                              void* d_out, int out_size, void* d_ws, size_t ws_size,
                              hipStream_t stream) {
  const float* feat0 = (const float*)d_in[0];
  const float* feat1 = (const float*)d_in[1];
  const float* Wq = (const float*)d_in[2];
  const float* bq = (const float*)d_in[3];
  const float* Wk = (const float*)d_in[4];
  const float* bk = (const float*)d_in[5];
  const float* Wv = (const float*)d_in[6];
  const float* bv = (const float*)d_in[7];
  const float* Wo = (const float*)d_in[8];
  const float* bo = (const float*)d_in[9];
  float* out = (float*)d_out;

  char* ws = (char*)d_ws;
  bf16* Wqb = (bf16*)(ws);
  bf16* Wkb = (bf16*)(ws + (1 << 19));
  bf16* Wvb = (bf16*)(ws + 2 * (size_t)(1 << 19));
  bf16* Wob = (bf16*)(ws + 3 * (size_t)(1 << 19));
  const size_t TEN = (size_t)8 * 4096 * 512 * 2;  // 33.55 MB per bf16 tensor
  char* p = ws + 4 * (size_t)(1 << 19);
  bf16* Xq  = (bf16*)(p);
  bf16* Xkv = (bf16*)(p + TEN);
  bf16* Qb  = (bf16*)(p + 2 * TEN);
  bf16* Kb  = (bf16*)(p + 3 * TEN);
  bf16* Vtb = (bf16*)(p + 4 * TEN);   // fp8 image (16 MB)
  bf16* ctx = Xq;  // Xq dead after Q projection

  convw_k<<<256, 256, 0, stream>>>(Wq, Wqb);
  convw_k<<<256, 256, 0, stream>>>(Wk, Wkb);
  convw_k<<<256, 256, 0, stream>>>(Wv, Wvb);
  convw_k<<<256, 256, 0, stream>>>(Wo, Wob);
  tconv_k<<<dim3(128, 16, 16), dim3(32, 8), 0, stream>>>(feat0, feat1, Xq, Xkv);
  gemm_k<0><<<dim3(128, 8), 256, 0, stream>>>(Xq,  Wqb, bq, Qb,  nullptr, nullptr);
  gemm_k<0><<<dim3(128, 8), 256, 0, stream>>>(Xkv, Wkb, bk, Kb,  nullptr, nullptr);
  gemm_k<1><<<dim3(128, 8), 256, 0, stream>>>(Xkv, Wvb, bv, Vtb, nullptr, nullptr);
  flash_k<<<dim3(256), dim3(512), 0, stream>>>(Qb, Kb, (const u8*)Vtb, ctx);
  gemm_k<2><<<dim3(128, 8), 256, 0, stream>>>(ctx, Wob, bo, nullptr, out, feat0);
}

// Round 12
// 469.403 us; speedup vs baseline: 1.6678x; 1.3289x over previous
//
#include <hip/hip_runtime.h>

#define AS1 __attribute__((address_space(1)))
#define AS3 __attribute__((address_space(3)))

typedef __bf16 bf16;
typedef unsigned char u8;
typedef unsigned int u32;
typedef __bf16 bf16x8 __attribute__((ext_vector_type(8)));
typedef __bf16 bf16x4v __attribute__((ext_vector_type(4)));
typedef float  f32x4  __attribute__((ext_vector_type(4)));
typedef long   i64x2  __attribute__((ext_vector_type(2)));

#define MFMA16(a,b,c) __builtin_amdgcn_mfma_f32_16x16x32_bf16((a),(b),(c),0,0,0)
#define MFMAF8(a,b,c) __builtin_amdgcn_mfma_f32_16x16x32_fp8_fp8((a),(b),(c),0,0,0)
#define BARX() asm volatile("s_waitcnt lgkmcnt(0)\ns_barrier" ::: "memory")
#define VMW(n) asm volatile("s_waitcnt vmcnt(" #n ")" ::: "memory")

static __device__ __forceinline__ void gll16(const bf16* src, bf16* lds) {
  __builtin_amdgcn_global_load_lds((const AS1 void*)src, (AS3 void*)lds, 16, 0, 0);
}
static __device__ __forceinline__ void gll16b(const u8* src, u8* lds) {
  __builtin_amdgcn_global_load_lds((const AS1 void*)src, (AS3 void*)lds, 16, 0, 0);
}

// ---------------- Kernel 0: weights fp32 -> bf16 (all 4 in one launch) ----------------
__global__ void convw_k(const float* __restrict__ s0, const float* __restrict__ s1,
                        const float* __restrict__ s2, const float* __restrict__ s3,
                        bf16* __restrict__ d) {
  const int which = blockIdx.x >> 8;
  const float* s = (which == 0) ? s0 : (which == 1) ? s1 : (which == 2) ? s2 : s3;
  bf16* dd = d + ((size_t)which << 18);
  int i = ((blockIdx.x & 255) * 256 + threadIdx.x) * 4;
  float4 v = *(const float4*)(s + i);
  bf16x4v o;
  o[0] = (bf16)v.x; o[1] = (bf16)v.y; o[2] = (bf16)v.z; o[3] = (bf16)v.w;
  *(bf16x4v*)(dd + i) = o;
}

// ------------- Kernel 1: transpose+convert feat [B,C,4096] -> [B,4096,C] bf16 -------------
__global__ void tconv_k(const float* __restrict__ f0, const float* __restrict__ f1,
                        bf16* __restrict__ xq, bf16* __restrict__ xkv) {
  const int z = blockIdx.z;
  const int b = z & 7;
  const float* src = (z < 8) ? f0 : f1;
  bf16* dst = (z < 8) ? xq : xkv;
  const int n0 = blockIdx.x * 32, c0 = blockIdx.y * 32;
  __shared__ float tile[32][33];
  const int tx = threadIdx.x, ty = threadIdx.y;
  const size_t base = (size_t)b * 512 * 4096;
#pragma unroll
  for (int i = 0; i < 4; i++) {
    int c = ty + i * 8;
    tile[c][tx] = src[base + (size_t)(c0 + c) * 4096 + n0 + tx];
  }
  __syncthreads();
  const size_t ob = (size_t)b * 4096 * 512;
#pragma unroll
  for (int i = 0; i < 4; i++) {
    int n = ty + i * 8;
    dst[ob + (size_t)(n0 + n) * 512 + c0 + tx] = (bf16)tile[tx][n];
  }
}

// ------------- Kernel 2: generic GEMM  out[r,co] = sum_k A[r,k]*W[co,k] + bias[co] -------------
// MODE 0: out bf16 [B,4096,512] plain                  (Q, K)
// MODE 1: out fp8 e4m3 paired image (V): [B][tile=kv>>5][g=(kv&31)>>3]
//         [(co>>5)*256 + (co&15)*16 + ((co>>4)&1)*8 + (kv&7)]  — co/co+16 paired into 16B
// MODE 2: out fp32 transposed [B,512,4096] + residual feat0  (final)
template<int MODE>
__global__ __launch_bounds__(256) void gemm_k(const bf16* __restrict__ A, const bf16* __restrict__ W,
                                              const float* __restrict__ bias, bf16* __restrict__ outB,
                                              float* __restrict__ outF, const float* __restrict__ resid) {
  const int b = blockIdx.y;
  const int rt = blockIdx.x >> 2, ct = blockIdx.x & 3;
  const int r0 = rt * 128, c0 = ct * 128;
  const int t = threadIdx.x, w = t >> 6, l = t & 63;
  __shared__ alignas(16) bf16 As[128 * 32];
  __shared__ alignas(16) bf16 Bs[128 * 32];
  f32x4 acc[4][4];
  const f32x4 fzero = {0.f, 0.f, 0.f, 0.f};
#pragma unroll
  for (int m = 0; m < 4; m++)
#pragma unroll
    for (int n = 0; n < 4; n++) acc[m][n] = fzero;
  const bf16* Ab = A + (size_t)b * 4096 * 512 + (size_t)r0 * 512;
  const int wr = (w >> 1) * 64, wc = (w & 1) * 64;
  for (int kk = 0; kk < 16; kk++) {
    const int k0 = kk * 32;
#pragma unroll
    for (int h = 0; h < 2; h++) {
      const int rowbase = w * 32 + h * 16;
      const int row = rowbase + (l >> 2);
      const int cl = (l & 3) ^ ((row >> 1) & 3);
      gll16(Ab + (size_t)row * 512 + k0 + cl * 8, As + rowbase * 32);
      gll16(W + (size_t)(c0 + row) * 512 + k0 + cl * 8, Bs + rowbase * 32);
    }
    __syncthreads();
    bf16x8 af[4], bfr[4];
#pragma unroll
    for (int m = 0; m < 4; m++) {
      const int row = wr + m * 16 + (l & 15);
      af[m] = *(const bf16x8*)(As + row * 32 + (((l >> 4) ^ ((row >> 1) & 3)) << 3));
    }
#pragma unroll
    for (int n = 0; n < 4; n++) {
      const int row = wc + n * 16 + (l & 15);
      bfr[n] = *(const bf16x8*)(Bs + row * 32 + (((l >> 4) ^ ((row >> 1) & 3)) << 3));
    }
#pragma unroll
    for (int m = 0; m < 4; m++)
#pragma unroll
      for (int n = 0; n < 4; n++)
        acc[m][n] = MFMA16(af[m], bfr[n], acc[m][n]);
    __syncthreads();
  }
#pragma unroll
  for (int n = 0; n < 4; n++) {
    const int co = c0 + wc + n * 16 + (l & 15);
    const float bv = bias[co];
#pragma unroll
    for (int m = 0; m < 4; m++) {
      const int rb = r0 + wr + m * 16 + ((l >> 4) << 2);
      if constexpr (MODE == 0) {
#pragma unroll
        for (int i = 0; i < 4; i++)
          outB[(size_t)b * 4096 * 512 + (size_t)(rb + i) * 512 + co] = (bf16)(acc[m][n][i] + bv);
      } else if constexpr (MODE == 1) {
        // V paired image fp8 e4m3 (see header); 4 kv per int store
        int pw = 0;
        pw = __builtin_amdgcn_cvt_pk_fp8_f32(acc[m][n][0] + bv, acc[m][n][1] + bv, pw, false);
        pw = __builtin_amdgcn_cvt_pk_fp8_f32(acc[m][n][2] + bv, acc[m][n][3] + bv, pw, true);
        const int kvin = rb & 31;
        u8* ov = (u8*)outB;
        const size_t o = (((size_t)b * 128 + (rb >> 5)) * 4 + (kvin >> 3)) * 4096 +
                         (co >> 5) * 256 + (co & 15) * 16 + ((co >> 4) & 1) * 8 + (rb & 7);
        *(int*)(ov + o) = pw;
      } else {
        const size_t o = ((size_t)b * 512 + co) * 4096 + rb;
        float4 rv = *(const float4*)(resid + o);
        float4 ov;
        ov.x = acc[m][n][0] + bv + rv.x;
        ov.y = acc[m][n][1] + bv + rv.y;
        ov.z = acc[m][n][2] + bv + rv.z;
        ov.w = acc[m][n][3] + bv + rv.w;
        *(float4*)(outF + o) = ov;
      }
    }
  }
}

// ------------- Kernel 3: flash cross-attention (R8 champion + b128 paired V reads) -------------
// 8 waves x 16 q-rows = 128 q/block. Q [B,4096,512] bf16; K [B,4096,512] bf16 (source-swizzled
// staging); V fp8 paired image. Ring-3 K (96KB) + ring-3 V (48KB), single barrier, VMW(6).
__global__ __launch_bounds__(512, 2) void flash_k(const bf16* __restrict__ Q, const bf16* __restrict__ K,
                                                  const u8* __restrict__ Vt, bf16* __restrict__ ctx) {
  __shared__ alignas(16) bf16 Ks[3][32 * 512];   // 96 KB ring-3
  __shared__ alignas(16) u8   Vs[3][16384];      // 48 KB ring-3
  const int flat = blockIdx.x;
  const int fs = (flat & 7) * 32 + (flat >> 3);  // XCD swizzle (256 = 8*32, bijective)
  const int b = fs >> 5, n0 = (fs & 31) * 128;
  const int tid = threadIdx.x, w = tid >> 6, l = tid & 63;
  const int g = l >> 4, r16 = l & 15;
  const int kswz = r16 & 7;

  // Q fragments (B-operand): lane holds Q[n0+w*16+r16][f*32 + g*8 .. +7]
  bf16x8 qf[16];
  {
    const bf16* Qb = Q + ((size_t)b * 4096 + n0 + w * 16 + r16) * 512 + g * 8;
#pragma unroll
    for (int f = 0; f < 16; f++) qf[f] = *(const bf16x8*)(Qb + f * 32);
  }
  f32x4 acc[32];
  const f32x4 fz = {0.f, 0.f, 0.f, 0.f};
#pragma unroll
  for (int f = 0; f < 32; f++) acc[f] = fz;
  float mrow = -1e30f, lrow = 0.f;

  // staging offsets (tile-invariant). K: LDS row linear, source chunk ^ (row&7).
  int koff[4];
#pragma unroll
  for (int j = 0; j < 4; j++) {
    const int row = w * 4 + j;
    koff[j] = row * 512 + ((l ^ (row & 7)) << 3);
  }
  const int voff0 = w * 2048 + l * 16;           // V: fully linear (image pre-arranged)
  const bf16* Kg = K + (size_t)b * 4096 * 512;
  const u8* Vg = Vt + (size_t)b * 128 * 16384;
  VMW(0);  // drain qf loads so vmcnt counting below is exact

  // prologue: stage tile 0 into slot 0 (4 K ops + 2 V ops per wave)
#pragma unroll
  for (int j = 0; j < 4; j++) gll16(Kg + koff[j], &Ks[0][0] + (w * 4 + j) * 512);
#pragma unroll
  for (int j = 0; j < 2; j++) gll16b(Vg + voff0 + j * 1024, &Vs[0][0] + voff0 + j * 1024);

  int cur = 0, nxt = 1;
#pragma unroll 1
  for (int t = 0; t < 128; ++t) {
    // ---- stage tile t+1 into slot nxt (safe: slowest reader is tile t-1 in slot prv) ----
    if (t < 127) {
      const bf16* ks = Kg + (size_t)(t + 1) * 16384;
      const u8* vs = Vg + (size_t)(t + 1) * 16384;
      bf16* kd = &Ks[nxt][0];
      u8* vd = &Vs[nxt][0];
#pragma unroll
      for (int j = 0; j < 4; j++) gll16(ks + koff[j], kd + (w * 4 + j) * 512);
#pragma unroll
      for (int j = 0; j < 2; j++) gll16b(vs + voff0 + j * 1024, vd + voff0 + j * 1024);
      VMW(6);   // tile t's 6 ops complete; t+1's 6 stay in flight
    } else {
      VMW(0);
    }
    BARX();     // single barrier: all waves' tile-t data visible

    // ---- QK^T: S^T[key][q], 4 independent MFMA chains ----
    const bf16* kb0 = &Ks[cur][0] + r16 * 512;
    f32x4 sa = fz, sb = fz, sc2 = fz, sd = fz;
#pragma unroll
    for (int f2 = 0; f2 < 16; f2 += 2) {
      const int c0i = ((((f2 << 2) + g) ^ kswz) << 3);
      const int c1i = (((((f2 + 1) << 2) + g) ^ kswz) << 3);
      bf16x8 k0 = *(const bf16x8*)(kb0 + c0i);
      bf16x8 k1 = *(const bf16x8*)(kb0 + 16 * 512 + c0i);
      bf16x8 k2 = *(const bf16x8*)(kb0 + c1i);
      bf16x8 k3 = *(const bf16x8*)(kb0 + 16 * 512 + c1i);
      sa = MFMA16(k0, qf[f2], sa);
      sb = MFMA16(k1, qf[f2], sb);
      sc2 = MFMA16(k2, qf[f2 + 1], sc2);
      sd = MFMA16(k3, qf[f2 + 1], sd);
    }
    const f32x4 s0 = sa + sc2, s1 = sb + sd;   // lane(q=r16): keys 4g+i / 16+4g+i

    // ---- online softmax, defer-max THR=5 (P <= e^5 = 148 < fp8 max 448) ----
    float pmax = fmaxf(fmaxf(fmaxf(s0[0], s0[1]), fmaxf(s0[2], s0[3])),
                       fmaxf(fmaxf(s1[0], s1[1]), fmaxf(s1[2], s1[3])));
    pmax = fmaxf(pmax, __shfl_xor(pmax, 16));
    pmax = fmaxf(pmax, __shfl_xor(pmax, 32));
    if (!__all(pmax <= mrow + 5.0f)) {
      const float mnew = fmaxf(mrow, pmax);
      const float scl = __expf(mrow - mnew);
      mrow = mnew;
      lrow *= scl;
      const int sclI = __float_as_int(scl);
      f32x4 sc4;
#pragma unroll
      for (int i = 0; i < 4; i++)
        sc4[i] = __int_as_float(__builtin_amdgcn_ds_bpermute(((g << 2) + i) << 2, sclI));
#pragma unroll
      for (int f = 0; f < 32; f++) acc[f] *= sc4;
    }
    float p0[4], p1[4];
#pragma unroll
    for (int i = 0; i < 4; i++) { p0[i] = __expf(s0[i] - mrow); p1[i] = __expf(s1[i] - mrow); }
    float rs = (p0[0] + p0[1]) + (p0[2] + p0[3]) + (p1[0] + p1[1]) + (p1[2] + p1[3]);
    rs += __shfl_xor(rs, 16);
    rs += __shfl_xor(rs, 32);
    lrow += rs;

    // ---- pack P->fp8, redistribute to PV A-fragment (4 bpermutes, register-only) ----
    int w0 = 0, w1 = 0;
    w0 = __builtin_amdgcn_cvt_pk_fp8_f32(p0[0], p0[1], w0, false);
    w0 = __builtin_amdgcn_cvt_pk_fp8_f32(p0[2], p0[3], w0, true);
    w1 = __builtin_amdgcn_cvt_pk_fp8_f32(p1[0], p1[1], w1, false);
    w1 = __builtin_amdgcn_cvt_pk_fp8_f32(p1[2], p1[3], w1, true);
    const int addrA = (((g & 1) << 5) + r16) << 2;   // lane 32*(g&1) + r16
    const int addrB = addrA + 64;                    // +16 lanes
    const int a0 = __builtin_amdgcn_ds_bpermute(addrA, w0);
    const int b0 = __builtin_amdgcn_ds_bpermute(addrB, w0);
    const int a1 = __builtin_amdgcn_ds_bpermute(addrA, w1);
    const int b1 = __builtin_amdgcn_ds_bpermute(addrB, w1);
    const bool lo2 = (g < 2);
    const u32 pA = (u32)(lo2 ? a0 : a1);
    const u32 pB = (u32)(lo2 ? b0 : b1);
    const long pf = (long)(((unsigned long long)pB << 32) | pA);

    // ---- PV: acc += P(fp8) @ V(fp8 in LDS); paired b128 reads feed 2 MFMAs ----
    const u8* vb = &Vs[cur][0] + g * 4096 + r16 * 16;
    __builtin_amdgcn_s_setprio(1);
#pragma unroll
    for (int c2 = 0; c2 < 16; c2++) {
      const i64x2 vv = *(const i64x2*)(vb + c2 * 256);
      acc[2 * c2] = MFMAF8(pf, vv[0], acc[2 * c2]);
      acc[2 * c2 + 1] = MFMAF8(pf, vv[1], acc[2 * c2 + 1]);
    }
    __builtin_amdgcn_s_setprio(0);
    cur = nxt;
    nxt = (nxt == 2) ? 0 : nxt + 1;
  }

  // ---- epilogue: ctx = acc / lrow * C^-0.5 ----
  const float inv = 0.04419417382415922f / lrow;
  const int invI = __float_as_int(inv);
  float fin[4];
#pragma unroll
  for (int i = 0; i < 4; i++)
    fin[i] = __int_as_float(__builtin_amdgcn_ds_bpermute(((g << 2) + i) << 2, invI));
  const size_t ob = (size_t)b * 4096 * 512;
#pragma unroll
  for (int ct = 0; ct < 32; ct++) {
    const int c = (ct << 4) + r16;
#pragma unroll
    for (int i = 0; i < 4; i++) {
      const int n = n0 + w * 16 + (g << 2) + i;
      ctx[ob + (size_t)n * 512 + c] = (bf16)(acc[ct][i] * fin[i]);
    }
  }
}

extern "C" void kernel_launch(void* const* d_in, const int* in_sizes, int n_in,
                              void* d_out, int out_size, void* d_ws, size_t ws_size,
                              hipStream_t stream) {
  const float* feat0 = (const float*)d_in[0];
  const float* feat1 = (const float*)d_in[1];
  const float* Wq = (const float*)d_in[2];
  const float* bq = (const float*)d_in[3];
  const float* Wk = (const float*)d_in[4];
  const float* bk = (const float*)d_in[5];
  const float* Wv = (const float*)d_in[6];
  const float* bv = (const float*)d_in[7];
  const float* Wo = (const float*)d_in[8];
  const float* bo = (const float*)d_in[9];
  float* out = (float*)d_out;

  char* ws = (char*)d_ws;
  bf16* Wqb = (bf16*)(ws);
  bf16* Wkb = (bf16*)(ws + (1 << 19));
  bf16* Wvb = (bf16*)(ws + 2 * (size_t)(1 << 19));
  bf16* Wob = (bf16*)(ws + 3 * (size_t)(1 << 19));
  const size_t TEN = (size_t)8 * 4096 * 512 * 2;  // 33.55 MB per bf16 tensor
  char* p = ws + 4 * (size_t)(1 << 19);
  bf16* Xq  = (bf16*)(p);
  bf16* Xkv = (bf16*)(p + TEN);
  bf16* Qb  = (bf16*)(p + 2 * TEN);
  bf16* Kb  = (bf16*)(p + 3 * TEN);
  bf16* Vtb = (bf16*)(p + 4 * TEN);   // fp8 paired image (16 MB)
  bf16* ctx = Xq;  // Xq dead after Q projection

  convw_k<<<1024, 256, 0, stream>>>(Wq, Wk, Wv, Wo, Wqb);
  tconv_k<<<dim3(128, 16, 16), dim3(32, 8), 0, stream>>>(feat0, feat1, Xq, Xkv);
  gemm_k<0><<<dim3(128, 8), 256, 0, stream>>>(Xq,  Wqb, bq, Qb,  nullptr, nullptr);
  gemm_k<0><<<dim3(128, 8), 256, 0, stream>>>(Xkv, Wkb, bk, Kb,  nullptr, nullptr);
  gemm_k<1><<<dim3(128, 8), 256, 0, stream>>>(Xkv, Wvb, bv, Vtb, nullptr, nullptr);
  flash_k<<<dim3(256), dim3(512), 0, stream>>>(Qb, Kb, (const u8*)Vtb, ctx);
  gemm_k<2><<<dim3(128, 8), 256, 0, stream>>>(ctx, Wob, bo, nullptr, out, feat0);
}